// Round 8
// baseline (21.384 us; speedup 1.0000x reference)
//
#include <hip/hip_runtime.h>
#include <math.h>

#define NN 1024
#define DE 64
#define DCAT 22
#define GC 2
#define NTC 512
#define NWAVE (NTC/64)   // 8
#define NBLK (NN/GC)     // 512

// ws float offsets
#define OFF_XT   0                    // [6][NN]   node features transposed
#define OFF_VIT  (OFF_XT + 6*NN)      // [16][NN]  Vi = X@Wv_i transposed
#define OFF_GR   (OFF_VIT + 16*NN)    // [NN]
#define OFF_GV   (OFF_GR + NN)        // [NN]
#define OFF_QREC (OFF_GV + NN)        // [32][NN] rows 0-5 qi2, 8-13 qr, 16-31 qv2 (scales folded)

// Full-wave (64-lane) sum via DPP; result valid in lane 63. Pure VALU.
__device__ __forceinline__ float wave_sum(float v) {
    int t;
    t = __builtin_amdgcn_update_dpp(0, __float_as_int(v), 0x111, 0xf, 0xf, true); v += __int_as_float(t);
    t = __builtin_amdgcn_update_dpp(0, __float_as_int(v), 0x112, 0xf, 0xf, true); v += __int_as_float(t);
    t = __builtin_amdgcn_update_dpp(0, __float_as_int(v), 0x114, 0xf, 0xf, true); v += __int_as_float(t);
    t = __builtin_amdgcn_update_dpp(0, __float_as_int(v), 0x118, 0xf, 0xf, true); v += __int_as_float(t);
    t = __builtin_amdgcn_update_dpp(0, __float_as_int(v), 0x142, 0xf, 0xf, true); v += __int_as_float(t);
    t = __builtin_amdgcn_update_dpp(0, __float_as_int(v), 0x143, 0xf, 0xf, true); v += __int_as_float(t);
    return v;
}

// Single block: weight contraction (Mi, M, u) + all per-node precompute.
__global__ __launch_bounds__(1024) void nce_setup(
    const float* __restrict__ nc,
    const float* __restrict__ Wq_i, const float* __restrict__ Wk_i,
    const float* __restrict__ Wv_i, const float* __restrict__ Wq_e,
    const float* __restrict__ Wk_e, const float* __restrict__ Wv_e,
    const float* __restrict__ wg, float* __restrict__ ws)
{
    __shared__ float s_wqi[96], s_wki[96], s_wvi[96];
    __shared__ float s_wqe[384], s_wke[1408], s_wve[1408], s_wg[64];
    __shared__ float s_M[6*DCAT], s_Mi[36], s_u[DCAT];
    const int tid = threadIdx.x;

    if (tid < 96) { s_wqi[tid]=Wq_i[tid]; s_wki[tid]=Wk_i[tid]; s_wvi[tid]=Wv_i[tid]; }
    { int t = tid - 128; if (t >= 0 && t < 384) s_wqe[t] = Wq_e[t]; }
    { int t = tid - 512; if (t >= 0 && t < 64)  s_wg[t]  = wg[t]; }
    for (int i = tid; i < 1408; i += 1024) { s_wke[i]=Wk_e[i]; s_wve[i]=Wv_e[i]; }
    __syncthreads();

    if (tid < 132) {                            // M[f][k] = (Wq_e Wk_e^T)[f,k] / 8
        const int f = tid % 6, k = tid / 6;
        float a = 0.f;
        #pragma unroll
        for (int d = 0; d < 64; ++d) a += s_wqe[f*64+d]*s_wke[k*64+d];
        s_M[f*DCAT+k] = a * 0.125f;
    } else if (tid < 168) {                     // Mi[g][f] = (Wq_i Wk_i^T)[g,f] / 4
        const int t = tid - 132, g = t % 6, f = t / 6;
        float a = 0.f;
        #pragma unroll
        for (int j = 0; j < 16; ++j) a += s_wqi[g*16+j]*s_wki[f*16+j];
        s_Mi[g*6+f] = a * 0.25f;
    } else if (tid < 190) {                     // u[k] = Wv_e[k,:]·wg
        const int k = tid - 168;
        float a = 0.f;
        #pragma unroll
        for (int d = 0; d < 64; ++d) a += s_wve[k*64+d]*s_wg[d];
        s_u[k] = a;
    }
    __syncthreads();

    const int n = tid;                          // one node per thread
    float x[6];
    #pragma unroll
    for (int f = 0; f < 6; ++f) { x[f] = nc[n*6 + f]; ws[OFF_XT + f*NN + n] = x[f]; }

    float vi[16];
    #pragma unroll
    for (int j = 0; j < 16; ++j) {
        float a = 0.f;
        #pragma unroll
        for (int f = 0; f < 6; ++f) a += x[f]*s_wvi[f*16+j];
        vi[j] = a;
        ws[OFF_VIT + j*NN + n] = a;
    }
    float gr = 0.f, gv = 0.f;
    #pragma unroll
    for (int f = 0; f < 6; ++f)  gr += x[f]*s_u[f];
    #pragma unroll
    for (int j = 0; j < 16; ++j) gv += vi[j]*s_u[6+j];
    ws[OFF_GR + n] = gr;
    ws[OFF_GV + n] = gv;

    #pragma unroll
    for (int f = 0; f < 6; ++f) {               // qi2 (stage-1 query, as centre n)
        float a = 0.f;
        #pragma unroll
        for (int g = 0; g < 6; ++g) a += x[g]*s_Mi[g*6+f];
        ws[OFF_QREC + f*NN + n] = a;
    }
    #pragma unroll
    for (int k = 0; k < DCAT; ++k) {            // qr (k<6) / qv2 (k>=6)
        float a = 0.f;
        #pragma unroll
        for (int f = 0; f < 6; ++f) a += x[f]*s_M[f*DCAT+k];
        ws[OFF_QREC + ((k < 6) ? (8+k) : (10+k))*NN + n] = a;
    }
}

__global__ __launch_bounds__(NTC, 4) void nce_centre(
    const float* __restrict__ ws, const float* __restrict__ bgp,
    const float* __restrict__ Wv_e, float* __restrict__ out)
{
    __shared__ float  s_wve[DCAT*DE];          // 5.5 KB
    __shared__ float  s_q[GC][32];
    __shared__ float2 s_red1[NWAVE], s_red2[NWAVE];
    __shared__ float2 s_acc[NWAVE][DCAT];
    __shared__ float  s_fin[DCAT*GC];

    const int tid = threadIdx.x, wave = tid >> 6, lane = tid & 63;
    const int c0 = blockIdx.x*GC;

    for (int i = tid; i < DCAT*DE; i += NTC) s_wve[i] = Wv_e[i];
    if (tid < GC*32) s_q[tid >> 5][tid & 31] = ws[OFF_QREC + (tid & 31)*NN + c0 + (tid >> 5)];

    const int nA = tid, nB = tid + NTC;
    float xA[6], xB[6], viA[16], viB[16];
    #pragma unroll
    for (int f = 0; f < 6; ++f) { xA[f] = ws[OFF_XT + f*NN + nA]; xB[f] = ws[OFF_XT + f*NN + nB]; }
    #pragma unroll
    for (int j = 0; j < 16; ++j) { viA[j] = ws[OFF_VIT + j*NN + nA]; viB[j] = ws[OFF_VIT + j*NN + nB]; }
    const float grA = ws[OFF_GR + nA], grB = ws[OFF_GR + nB];
    const float gvA = ws[OFF_GV + nA], gvB = ws[OFF_GV + nB];
    const float bg = *bgp;
    __syncthreads();

    // ---------------- stage 1: a_i = softmax_n(qi2[c]·x[n]) ----------------
    float aiA[GC], aiB[GC];
    #pragma unroll
    for (int c = 0; c < GC; ++c) {
        const float* q = s_q[c];
        float sA = 0.f, sB = 0.f;
        #pragma unroll
        for (int f = 0; f < 6; ++f) { sA += q[f]*xA[f]; sB += q[f]*xB[f]; }
        aiA[c] = __expf(sA); aiB[c] = __expf(sB);
    }
    {
        float r0 = wave_sum(aiA[0]+aiB[0]);
        float r1 = wave_sum(aiA[1]+aiB[1]);
        if (lane == 63) s_red1[wave] = make_float2(r0, r1);
    }
    __syncthreads();
    {
        float2 dd = s_red1[0];
        #pragma unroll
        for (int w2 = 1; w2 < NWAVE; ++w2) { float2 t = s_red1[w2]; dd.x += t.x; dd.y += t.y; }
        float inv0 = 1.f/dd.x, inv1 = 1.f/dd.y;
        aiA[0] *= inv0; aiB[0] *= inv0; aiA[1] *= inv1; aiB[1] *= inv1;
    }

    // --------- stage 2: a_e = softmax_n(qr·x + ai*(qv2·Vi)); gate -> w1,w2 ---------
    float w1A[GC], w2A[GC], w1B[GC], w2B[GC];
    {
        float eA[GC], eB[GC];
        #pragma unroll
        for (int c = 0; c < GC; ++c) {
            const float* q = s_q[c];
            float uA = 0.f, uB = 0.f, vA = 0.f, vB = 0.f;
            #pragma unroll
            for (int f = 0; f < 6; ++f) { uA += q[8+f]*xA[f]; uB += q[8+f]*xB[f]; }
            #pragma unroll
            for (int j = 0; j < 16; ++j) { vA += q[16+j]*viA[j]; vB += q[16+j]*viB[j]; }
            eA[c] = __expf(uA + aiA[c]*vA);
            eB[c] = __expf(uB + aiB[c]*vB);
        }
        float s0 = wave_sum(eA[0]+eB[0]);
        float s1 = wave_sum(eA[1]+eB[1]);
        if (lane == 63) s_red2[wave] = make_float2(s0, s1);
        __syncthreads();
        float2 dd = s_red2[0];
        #pragma unroll
        for (int w2 = 1; w2 < NWAVE; ++w2) { float2 t = s_red2[w2]; dd.x += t.x; dd.y += t.y; }
        float den[GC] = {dd.x, dd.y};
        #pragma unroll
        for (int c = 0; c < GC; ++c) {
            float inv = 1.f/den[c];
            float aeA = eA[c]*inv, aeB = eB[c]*inv;
            float preA = aeA*(grA + aiA[c]*gvA) + bg;
            float preB = aeB*(grB + aiB[c]*gvB) + bg;
            float gA = 1.f/(1.f + __expf(-preA));
            float gB = 1.f/(1.f + __expf(-preB));
            w1A[c] = gA*aeA; w2A[c] = w1A[c]*aiA[c];
            w1B[c] = gB*aeB; w2B[c] = w1B[c]*aiB[c];
        }
    }

    // ------- stage 3: xbar[c] = Σ w1·x, vbar[c] = Σ w2·Vi  (DPP block reduce) -------
    #pragma unroll
    for (int f = 0; f < 6; ++f) {
        float a0 = wave_sum(w1A[0]*xA[f] + w1B[0]*xB[f]);
        float a1 = wave_sum(w1A[1]*xA[f] + w1B[1]*xB[f]);
        if (lane == 63) s_acc[wave][f] = make_float2(a0, a1);
    }
    #pragma unroll
    for (int j = 0; j < 16; ++j) {
        float a0 = wave_sum(w2A[0]*viA[j] + w2B[0]*viB[j]);
        float a1 = wave_sum(w2A[1]*viA[j] + w2B[1]*viB[j]);
        if (lane == 63) s_acc[wave][6+j] = make_float2(a0, a1);
    }
    __syncthreads();
    if (tid < DCAT*GC) {                        // 44 threads: sum wave partials
        const int k = tid >> 1, c = tid & 1;
        float a = 0.f;
        #pragma unroll
        for (int w2 = 0; w2 < NWAVE; ++w2)
            a += ((const float*)&s_acc[w2][k])[c];
        s_fin[k*GC + c] = a;
    }
    __syncthreads();

    // ---------------- epilogue: out[c,:] = Wv_e^T [xbar; vbar] ----------------
    if (tid < GC*DE) {
        const int c = tid >> 6, d = tid & 63;
        float o = 0.f;
        #pragma unroll
        for (int k = 0; k < DCAT; ++k) o += s_fin[k*GC + c]*s_wve[k*64 + d];
        out[(c0 + c)*DE + d] = o;
    }
}

extern "C" void kernel_launch(void* const* d_in, const int* in_sizes, int n_in,
                              void* d_out, int out_size, void* d_ws, size_t ws_size,
                              hipStream_t stream)
{
    const float* nc   = (const float*)d_in[0];
    const float* Wq_i = (const float*)d_in[1];
    const float* Wk_i = (const float*)d_in[2];
    const float* Wv_i = (const float*)d_in[3];
    const float* Wq_e = (const float*)d_in[4];
    const float* Wk_e = (const float*)d_in[5];
    const float* Wv_e = (const float*)d_in[6];
    const float* wg   = (const float*)d_in[7];
    const float* bg   = (const float*)d_in[8];
    float* out = (float*)d_out;
    float* ws  = (float*)d_ws;

    nce_setup<<<1, 1024, 0, stream>>>(nc, Wq_i, Wk_i, Wv_i, Wq_e, Wk_e, Wv_e, wg, ws);
    nce_centre<<<NBLK, NTC, 0, stream>>>(ws, bg, Wv_e, out);
}